// Round 14
// baseline (130.786 us; speedup 1.0000x reference)
//
#include <hip/hip_runtime.h>
#include <hip/hip_bf16.h>
#include <hip/hip_cooperative_groups.h>

namespace cg = cooperative_groups;

// B=16, Ci=16, Co=16, H=W=24, hidden=64.
// kt:    K[dy47][dxi][o][i] bf16; dy47 = dy+23 in [0,47), dxi = dx+24 in [0,49).
//        dxi stride = 256 shorts.
// vpad2: bf16 [y'=40][x'=40][b=16][i=16], y'=h+8, x'=w+8, zero halo.
// r14: single cooperative kernel, 252 blocks x 512 thr, 2 grid syncs:
//   A: vpad (grid-stride) + kt (blocks 0..143, 16 rows each)
//   B: r12 sliding-A conv -> part[oct][p][c2]   (NO atomics -- r13 lesson)
//   C: combine (blocks 0..143, 4 p each): sum 7 octs, scale, +bias, float4 out.

typedef __attribute__((ext_vector_type(8))) short bf16x8;
typedef __attribute__((ext_vector_type(4))) float f32x4;

#define KT_ELEMS (47*49*256)          // 589,568 bf16
#define VPAD2_ELEMS (40*40*256)       // 409,600 bf16
#define NROWS (47*49)                 // 2303 MLP rows
#define NPOS 576                      // 24*24 output positions
#define NOCT 7                        // dy octets (7*4 = 28 >= 27)
#define GRID 252
#define THREADS 512

__launch_bounds__(512)
__global__ void fused(const float* __restrict__ v,
                      const float* __restrict__ w1, const float* __restrict__ b1,
                      const float* __restrict__ w2, const float* __restrict__ b2,
                      const float* __restrict__ bias,
                      __hip_bfloat16* __restrict__ kt_, __hip_bfloat16* __restrict__ vpad_,
                      float* __restrict__ part, float* __restrict__ out)
{
    __shared__ __align__(16) char smem[32768];   // A: hid+tables; B: red; C: lds2
    const int tid = threadIdx.x;
    const int bid = blockIdx.x;

    // ---------------- Phase A: vpad + kt ----------------
    for (int idx = bid*THREADS + tid; idx < VPAD2_ELEMS; idx += GRID*THREADS) {
        int i = idx & 15;
        int b = (idx >> 4) & 15;
        int s = idx >> 8;             // y*40 + x
        int x = s % 40;
        int y = s / 40;
        int h = y - 8, w = x - 8;
        float val = 0.0f;
        if (h >= 0 && h < 24 && w >= 0 && w < 24)
            val = v[((b*16 + i)*24 + h)*24 + w];
        vpad_[idx] = __float2bfloat16(val);
    }

    if (bid < 144) {                  // kt: 16 rows of [2303 x 256] GEMM
        float* hid = (float*)smem;    // [16][64]
        float* tys = hid + 16*64;     // [47]
        float* txs = tys + 47;        // [49]
        if (tid < 47)               tys[tid]    = tanhf((float)(tid - 23)*(1.0f/6.0f));
        if (tid >= 64 && tid < 113) txs[tid-64] = tanhf((float)(tid - 64 - 24)*(1.0f/6.0f));
        __syncthreads();

        const int r0 = bid * 16;
        #pragma unroll
        for (int k = 0; k < 2; ++k) {
            int idx = k*THREADS + tid;          // 0..1023 = 16 rows x 64 j
            int rr = idx >> 6, j = idx & 63;
            int r = r0 + rr; if (r >= NROWS) r = NROWS - 1;
            int dy47 = r / 49, dxi = r % 49;
            float x = tys[dy47]*w1[2*j] + txs[dxi]*w1[2*j+1] + b1[j];
            hid[rr*64 + j] = 0.5f*x*(1.0f + erff(x*0.70710678118f));
        }
        __syncthreads();

        const int c    = tid & 255;
        const int half = tid >> 8;    // rows half*8 .. half*8+7
        float acc[8];
        const float bb = b2[c];
        #pragma unroll
        for (int r = 0; r < 8; ++r) acc[r] = bb;
        const float4* w2v = (const float4*)w2;
        #pragma unroll
        for (int jv = 0; jv < 16; ++jv) {
            float4 wv = w2v[c*16 + jv];
            #pragma unroll
            for (int e = 0; e < 4; ++e) {
                float we = ((const float*)&wv)[e];
                int j = jv*4 + e;
                #pragma unroll
                for (int r = 0; r < 8; ++r)
                    acc[r] += hid[(half*8 + r)*64 + j] * we;
            }
        }
        #pragma unroll
        for (int rr = 0; rr < 8; ++rr) {
            int r = r0 + half*8 + rr;
            if (r < NROWS) kt_[r*256 + c] = __float2bfloat16(acc[rr]);
        }
    }

    cg::this_grid().sync();

    // ---------------- Phase B: sliding-A MFMA conv -> part ----------------
    {
        typedef f32x4 (*redT)[4][64];
        redT red = (redT)smem;        // [8][4][64] f32x4 = 32 KB
        const short* kt = (const short*)kt_;
        const short* vp = (const short*)vpad_;

        const int oct = bid / 36;     // 0..6
        const int rem = bid % 36;
        const int hg  = rem / 6;      // 0..5
        const int wt  = rem % 6;      // 0..5
        const int w0  = wt * 4;
        const int h0  = hg * 4;

        const int lane = tid & 63;
        const int wv   = tid >> 6;    // 0..7
        const int tq   = wv & 3;
        const int hhh  = wv >> 2;
        const int n    = lane & 15;
        const int g    = lane >> 4;
        const int d    = g >> 1;
        const int ih   = (g & 1) * 8;

        const int t = oct*4 + tq;     // dy = t - h0 - 3, valid t < 27

        f32x4 acc[2][4];
        #pragma unroll
        for (int hh = 0; hh < 2; ++hh)
            #pragma unroll
            for (int ww = 0; ww < 4; ++ww) acc[hh][ww] = (f32x4){0.f,0.f,0.f,0.f};

        if (t < 27) {
            const int dy47 = t - h0 + 20;                       // in [0,46]
            const short* apb = kt + ((long)(dy47*49 + (24 - w0 + d)))*256 + n*16 + ih;
            const short* bpb = vp + ((long)((t + hhh*2 + 5)*40 + (8 + d)))*256 + n*16 + ih;

            bf16x8 av[4];
            av[0] = *(const bf16x8*)(apb);        // dxi = 24-w0+d
            av[1] = *(const bf16x8*)(apb - 256);
            av[2] = *(const bf16x8*)(apb - 512);
            av[3] = *(const bf16x8*)(apb - 768);

            #pragma unroll
            for (int dxp = 0; dxp < 12; ++dxp) {
                bf16x8 bv0 = *(const bf16x8*)(bpb +         dxp*512);
                bf16x8 bv1 = *(const bf16x8*)(bpb + 10240 + dxp*512);
                #pragma unroll
                for (int ww = 0; ww < 4; ++ww) {
                    acc[0][ww] = __builtin_amdgcn_mfma_f32_16x16x32_bf16(av[ww], bv0, acc[0][ww], 0, 0, 0);
                    acc[1][ww] = __builtin_amdgcn_mfma_f32_16x16x32_bf16(av[ww], bv1, acc[1][ww], 0, 0, 0);
                }
                if (dxp < 11) {
                    av[2] = av[0];
                    av[3] = av[1];
                    av[0] = *(const bf16x8*)(apb + (2*dxp + 2)*256);
                    av[1] = *(const bf16x8*)(apb + (2*dxp + 1)*256);
                }
            }
        }

        #pragma unroll
        for (int hh = 0; hh < 2; ++hh) {
            if (hh) __syncthreads();
            #pragma unroll
            for (int ww = 0; ww < 4; ++ww) red[wv][ww][lane] = acc[hh][ww];
            __syncthreads();

            const int hhh2 = wv >> 2;
            const int ww2  = wv & 3;
            f32x4 s = red[4*hhh2 + 0][ww2][lane];
            s += red[4*hhh2 + 1][ww2][lane];
            s += red[4*hhh2 + 2][ww2][lane];
            s += red[4*hhh2 + 3][ww2][lane];

            const int h = h0 + hhh2*2 + hh;
            const int w = w0 + ww2;
            const int p = h*24 + w;
            float* dst = part + ((size_t)oct*NPOS + p)*256 + (n*16 + g*4);
            *(f32x4*)dst = s;
        }
    }

    cg::this_grid().sync();

    // ---------------- Phase C: combine (blocks 0..143, 4 p each) ----------
    if (bid < 144) {
        float* lds2 = (float*)smem;   // [4][260]
        const int p0 = bid * 4;
        const int cc = tid & 255;
        const int pq = tid >> 8;      // p-half
        #pragma unroll
        for (int pp2 = 0; pp2 < 2; ++pp2) {
            int pp = pq*2 + pp2;
            float s = 0.f;
            #pragma unroll
            for (int oct = 0; oct < NOCT; ++oct)
                s += part[((size_t)oct*NPOS + p0 + pp)*256 + cc];
            lds2[pp*260 + cc] = s;
        }
        __syncthreads();
        if (tid < 256) {
            const float sc = 1.0f/576.0f;
            const int c2 = tid;
            const float bb = bias[c2 & 15];
            float4 o;
            o.x = lds2[0*260 + c2]*sc + bb;
            o.y = lds2[1*260 + c2]*sc + bb;
            o.z = lds2[2*260 + c2]*sc + bb;
            o.w = lds2[3*260 + c2]*sc + bb;
            *(float4*)(out + (size_t)c2*NPOS + p0) = o;
        }
    }
}

extern "C" void kernel_launch(void* const* d_in, const int* in_sizes, int n_in,
                              void* d_out, int out_size, void* d_ws, size_t ws_size,
                              hipStream_t stream)
{
    const float* v    = (const float*)d_in[0];
    const float* w1   = (const float*)d_in[1];
    const float* b1   = (const float*)d_in[2];
    const float* w2   = (const float*)d_in[3];
    const float* b2   = (const float*)d_in[4];
    const float* bias = (const float*)d_in[5];
    float* out = (float*)d_out;

    char* ws = (char*)d_ws;
    __hip_bfloat16* kt   = (__hip_bfloat16*)ws;                          // 1,179,136 B
    __hip_bfloat16* vpad = (__hip_bfloat16*)(ws + (size_t)KT_ELEMS*2);   //   819,200 B
    float* part = (float*)(ws + (size_t)KT_ELEMS*2 + (size_t)VPAD2_ELEMS*2); // 4,128,768 B

    void* args[] = {(void*)&v, (void*)&w1, (void*)&b1, (void*)&w2, (void*)&b2,
                    (void*)&bias, (void*)&kt, (void*)&vpad, (void*)&part, (void*)&out};
    hipLaunchCooperativeKernel((const void*)fused, dim3(GRID), dim3(THREADS),
                               args, 0, stream);
}

// Round 16
// 25.564 us; speedup vs baseline: 5.1160x; 5.1160x over previous
//
#include <hip/hip_runtime.h>
#include <hip/hip_bf16.h>

// B=16, Ci=16, Co=16, H=W=24, hidden=64.
// kt:    K[dy47][dxi][o][i] bf16; dy47 = dy+23 in [0,47), dxi = dx+24 in [0,49).
//        dxi stride = 256 shorts.
// vpad2: bf16 [y'=40][x'=40][b=16][i=16], y'=h+8, x'=w+8, zero halo.
// r15 (= r12 structure + conv feed fix): 3 kernels, no atomics (r13 lesson),
//   no cooperative sync (r14 lesson: 2 grid syncs cost ~90 µs).
//   conv: A staged in LDS (4 dy rows x 27 dxi, 55 KB, dedups hhh-pair loads);
//   B fully register-prefetched (24 x bf16x8) before the MFMA loop.

typedef __attribute__((ext_vector_type(8))) short bf16x8;
typedef __attribute__((ext_vector_type(4))) float f32x4;

#define KT_ELEMS (47*49*256)          // 589,568 bf16
#define VPAD2_ELEMS (40*40*256)       // 409,600 bf16
#define NROWS (47*49)                 // 2303 MLP rows
#define NPOS 576                      // 24*24 output positions
#define NOCT 7                        // dy octets (7*4 = 28 >= 27)
#define PREP_BUILD_BLOCKS 288         // ceil(2303/8)
#define PREP_PAD_BLOCKS (VPAD2_ELEMS/256)   // 1600

// ---------------- Kernel 1: prep = build K table + pad v (fused grid) -------
__launch_bounds__(256)
__global__ void prep(const float* __restrict__ v,
                     const float* __restrict__ w1, const float* __restrict__ b1,
                     const float* __restrict__ w2, const float* __restrict__ b2,
                     __hip_bfloat16* __restrict__ kt, __hip_bfloat16* __restrict__ vpad)
{
    const int tid = threadIdx.x;

    if (blockIdx.x >= PREP_BUILD_BLOCKS) {
        // ---- pad part: vpad2[y][x][b][i] ----
        int idx = (blockIdx.x - PREP_BUILD_BLOCKS)*256 + tid;
        if (idx >= VPAD2_ELEMS) return;
        int i = idx & 15;
        int b = (idx >> 4) & 15;
        int s = idx >> 8;             // y*40 + x
        int x = s % 40;
        int y = s / 40;
        int h = y - 8, w = x - 8;
        float val = 0.0f;
        if (h >= 0 && h < 24 && w >= 0 && w < 24)
            val = v[((b*16 + i)*24 + h)*24 + w];
        vpad[idx] = __float2bfloat16(val);
        return;
    }

    // ---- build part: 8 rows of the [2303 x 256] K GEMM per block ----
    __shared__ float ty_s[47];
    __shared__ float tx_s[49];
    __shared__ float hid_s[8][64];
    const int r0 = blockIdx.x * 8;

    if (tid < 47)               ty_s[tid]      = tanhf((float)(tid - 23) * (1.0f/6.0f));
    if (tid >= 64 && tid < 113) tx_s[tid - 64] = tanhf((float)(tid - 64 - 24) * (1.0f/6.0f));
    __syncthreads();

    #pragma unroll
    for (int k = 0; k < 2; ++k) {
        int idx = k*256 + tid;
        int rr  = idx >> 6;
        int j   = idx & 63;
        int r   = r0 + rr;
        if (r >= NROWS) r = NROWS - 1;
        int dy47 = r / 49;
        int dxi  = r % 49;
        float x = ty_s[dy47]*w1[2*j] + tx_s[dxi]*w1[2*j+1] + b1[j];
        hid_s[rr][j] = 0.5f*x*(1.0f + erff(x*0.70710678118f));
    }
    __syncthreads();

    const int c = tid;
    float acc[8];
    const float bb = b2[c];
    #pragma unroll
    for (int r = 0; r < 8; ++r) acc[r] = bb;

    const float4* w2v = (const float4*)w2;
    #pragma unroll
    for (int jv = 0; jv < 16; ++jv) {
        float4 wv = w2v[c*16 + jv];
        #pragma unroll
        for (int e = 0; e < 4; ++e) {
            float we = ((const float*)&wv)[e];
            int j = jv*4 + e;
            #pragma unroll
            for (int r = 0; r < 8; ++r)
                acc[r] += hid_s[r][j] * we;
        }
    }

    #pragma unroll
    for (int rr = 0; rr < 8; ++rr) {
        int r = r0 + rr;
        if (r >= NROWS) break;
        kt[r*256 + c] = __float2bfloat16(acc[rr]);
    }
}

// ---------------- Kernel 2: MFMA conv, LDS-A + reg-B prefetch ----------------
// grid (wt6, hg6, oct7), 512 thr = 8 waves = (tq 0..3) x (hhh 0..1).
// A(ww,dxp): dxi = 24 - w0 - ww + 2*dxp + d  -> dxi_local = 3 + d + 2dxp - ww,
// dxi_local in [0,27). a_lds[dy_local 0..3][dxi_local 0..26][c 0..255].
__launch_bounds__(512)
__global__ void conv_part(const __hip_bfloat16* __restrict__ kt_,
                          const __hip_bfloat16* __restrict__ vpad_,
                          float* __restrict__ part)
{
    __shared__ short a_lds[4*27*256]; // 55,296 B
    __shared__ f32x4 red[8][4][64];   // 32 KB
    const short* kt = (const short*)kt_;
    const short* vp = (const short*)vpad_;

    const int wt  = blockIdx.x;       // 0..5  -> w0 = wt*4
    const int hg  = blockIdx.y;       // 0..5  -> h0 = hg*4
    const int oct = blockIdx.z;       // 0..6
    const int w0  = wt * 4;
    const int h0  = hg * 4;

    const int tid  = threadIdx.x;
    const int lane = tid & 63;
    const int wv   = tid >> 6;        // 0..7
    const int tq   = wv & 3;
    const int hhh  = wv >> 2;         // h-pair of this wave
    const int n    = lane & 15;       // A: o row; B: b col
    const int g    = lane >> 4;       // k-group
    const int d    = g >> 1;          // dx sub-offset within pair
    const int ih   = (g & 1) * 8;     // i-half

    // ---- stage A: 4 dy rows x 27 dxi x 256 c (16B chunks) ----
    const int dximin = 21 - w0;       // 24 - w0 - 3; >= 1
    for (int q = tid; q < 3456; q += 512) {
        int dyl = q / 864;            // 864 = 27*32 chunks per dy row
        int rem = q % 864;
        int dxl = rem / 32;
        int cch = rem % 32;
        int ts  = oct*4 + dyl;
        int dy47 = ts - h0 + 20;
        if (dy47 > 46) dy47 = 46;     // clamp (ts==27 rows unused)
        const bf16x8* src = (const bf16x8*)(kt + ((long)(dy47*49 + dximin + dxl))*256 + cch*8);
        *(bf16x8*)(a_lds + ((dyl*27 + dxl)*256 + cch*8)) = *src;
    }
    __syncthreads();

    const int t = oct*4 + tq;         // dy = t - h0 - 3, valid t < 27

    f32x4 acc[2][4];
    #pragma unroll
    for (int hh = 0; hh < 2; ++hh)
        #pragma unroll
        for (int ww = 0; ww < 4; ++ww) acc[hh][ww] = (f32x4){0.f,0.f,0.f,0.f};

    if (t < 27) {
        // ---- prefetch all B into registers: 24 x 16B, independent ----
        const short* bpb = vp + ((long)((t + hhh*2 + 5)*40 + (8 + d)))*256 + n*16 + ih;
        bf16x8 bv[2][12];
        #pragma unroll
        for (int hh = 0; hh < 2; ++hh)
            #pragma unroll
            for (int dxp = 0; dxp < 12; ++dxp)
                bv[hh][dxp] = *(const bf16x8*)(bpb + hh*10240 + dxp*512);

        // ---- A from LDS: slide + 2 ds_read refills per step ----
        const short* al = a_lds + (tq*27)*256 + n*16 + ih;   // + dxi_local*256
        bf16x8 av[4];
        av[0] = *(const bf16x8*)(al + (3 + d    )*256);      // ww=0, dxp=0
        av[1] = *(const bf16x8*)(al + (2 + d    )*256);      // ww=1
        av[2] = *(const bf16x8*)(al + (1 + d    )*256);      // ww=2
        av[3] = *(const bf16x8*)(al + (0 + d    )*256);      // ww=3

        #pragma unroll
        for (int dxp = 0; dxp < 12; ++dxp) {
            #pragma unroll
            for (int ww = 0; ww < 4; ++ww) {
                acc[0][ww] = __builtin_amdgcn_mfma_f32_16x16x32_bf16(av[ww], bv[0][dxp], acc[0][ww], 0, 0, 0);
                acc[1][ww] = __builtin_amdgcn_mfma_f32_16x16x32_bf16(av[ww], bv[1][dxp], acc[1][ww], 0, 0, 0);
            }
            if (dxp < 11) {
                av[2] = av[0];        // A(2,dxp+1) = A(0,dxp)
                av[3] = av[1];        // A(3,dxp+1) = A(1,dxp)
                av[0] = *(const bf16x8*)(al + (5 + d + 2*dxp)*256);  // ww=0,dxp+1
                av[1] = *(const bf16x8*)(al + (4 + d + 2*dxp)*256);  // ww=1,dxp+1
            }
        }
    }

    // Two-phase reduce (32 KB): phase hh stores acc[hh][*], then wave wv
    // (hhh2 = wv>>2, ww2 = wv&3) writes row h = h0 + hhh2*2 + hh.
    #pragma unroll
    for (int hh = 0; hh < 2; ++hh) {
        if (hh) __syncthreads();      // protect red reuse
        #pragma unroll
        for (int ww = 0; ww < 4; ++ww) red[wv][ww][lane] = acc[hh][ww];
        __syncthreads();

        const int hhh2 = wv >> 2;
        const int ww2  = wv & 3;
        f32x4 s = red[4*hhh2 + 0][ww2][lane];
        s += red[4*hhh2 + 1][ww2][lane];
        s += red[4*hhh2 + 2][ww2][lane];
        s += red[4*hhh2 + 3][ww2][lane];

        const int h = h0 + hhh2*2 + hh;
        const int w = w0 + ww2;
        const int p = h*24 + w;
        // part layout: [oct][p][b*16 + o], o = g*4+e contiguous -> f32x4
        float* dst = part + ((size_t)oct*NPOS + p)*256 + (n*16 + g*4);
        *(f32x4*)dst = s;
    }
}

// ---------------- Kernel 3: combine octets + scale + bias (transpose) -------
__launch_bounds__(256)
__global__ void combine(const float* __restrict__ part, const float* __restrict__ bias,
                        float* __restrict__ out)
{
    __shared__ float lds[16][257];
    const int tid = threadIdx.x;
    const int p0  = blockIdx.x * 16;

    #pragma unroll
    for (int pp = 0; pp < 16; ++pp) {
        float s = 0.f;
        #pragma unroll
        for (int oct = 0; oct < NOCT; ++oct)
            s += part[((size_t)oct*NPOS + p0 + pp)*256 + tid];
        lds[pp][tid] = s;
    }
    __syncthreads();

    const int pp = tid & 15;
    const int g  = tid >> 4;          // 0..15 across the block
    const float sc = 1.0f/576.0f;
    #pragma unroll
    for (int cc = 0; cc < 16; ++cc) {
        int c2 = cc*16 + g;           // c2 = b*16 + o
        out[(size_t)c2*576 + p0 + pp] = lds[pp][c2]*sc + bias[c2 & 15];
    }
}

extern "C" void kernel_launch(void* const* d_in, const int* in_sizes, int n_in,
                              void* d_out, int out_size, void* d_ws, size_t ws_size,
                              hipStream_t stream)
{
    const float* v    = (const float*)d_in[0];
    const float* w1   = (const float*)d_in[1];
    const float* b1   = (const float*)d_in[2];
    const float* w2   = (const float*)d_in[3];
    const float* b2   = (const float*)d_in[4];
    const float* bias = (const float*)d_in[5];
    float* out = (float*)d_out;

    char* ws = (char*)d_ws;
    __hip_bfloat16* kt   = (__hip_bfloat16*)ws;                          // 1,179,136 B
    __hip_bfloat16* vpad = (__hip_bfloat16*)(ws + (size_t)KT_ELEMS*2);   //   819,200 B
    float* part = (float*)(ws + (size_t)KT_ELEMS*2 + (size_t)VPAD2_ELEMS*2); // 4,128,768 B

    prep<<<dim3(PREP_BUILD_BLOCKS + PREP_PAD_BLOCKS), dim3(256), 0, stream>>>(
        v, w1, b1, w2, b2, kt, vpad);
    conv_part<<<dim3(6, 6, NOCT), dim3(512), 0, stream>>>(kt, vpad, part);
    combine<<<dim3(NPOS/16), dim3(256), 0, stream>>>(part, bias, out);
}